// Round 13
// baseline (84.633 us; speedup 1.0000x reference)
//
#include <hip/hip_runtime.h>
#include <math.h>

#define NPTS 8192
#define NB 4
#define BLK 256
#define MSEG 8          // ref segments per (b,dir); seg = 32 tiles = 1024 refs
#define QPW 4           // query tiles per wave (128 queries; 4 B-frags in regs)

typedef __attribute__((ext_vector_type(8))) short  short8v;  // 4 VGPRs = 8 bf16
typedef __attribute__((ext_vector_type(16))) float f32x16;   // MFMA 32x32 acc

__device__ __forceinline__ float min3f(float a, float b, float c) {
    float d;
    asm("v_min3_f32 %0, %1, %2, %3" : "=v"(d) : "v"(a), "v"(b), "v"(c));
    return d;
}
// RNE float->bf16 (no NaN inputs here)
__device__ __forceinline__ unsigned short f2bf(float f) {
    unsigned u = __float_as_uint(f);
    return (unsigned short)((u + 0x7FFFu + ((u >> 16) & 1u)) >> 16);
}
__device__ __forceinline__ float bf2f(unsigned short h) {
    return __uint_as_float(((unsigned)h) << 16);
}

// ---------------------------------------------------------------------------
// P1 (merged pack+mfma): the block's 1024-ref segment is read RAW from
// global (12 KB, L2-resident) and its A-fragments are built directly in
// LDS (32 KB, whole segment resident -> ONE barrier, no double-buffering,
// no apack array, no pack dispatch).
// K-slot pairing (A = refs, B = queries, m = -2q):
//  k0-2: rh_c * mh_c | k3-5: rl_c * mh_c | k6-8: rh_c * ml_c
//  k9:   w_h  * 1    | k10:  w_l  * 1    | k11-15: 0
// acc = (-2 q . r) + |r|^2 (|q|^2 added in reduce; min commutes).
// Per A-tile: lane l holds point (tile*32 + (l&31)), k-slots 8*(l>>5)..+7
// as one contiguous short8v. Each wave owns FOUR query tiles (B-frags in
// regs, built from raw floats with bitwise-identical split math) so every
// ds_read_b128 feeds 4 MFMAs. Min over the 16 in-lane rows is
// row-mapping-agnostic; C col = lane&31 (HW-verified m74/m101); finish
// with shfl_xor(32). Also zeroes out[0] (stream-ordered before reduce).
//
// NOTE (r10-r12): fusing reduce into this kernel via cooperative grid.sync
// failed 3x with a ~4% min-inflation signature INSENSITIVE to store/load
// atomicity flavor and grid shape; the two-dispatch structure (kernel
// boundary = full cache flush/invalidate) is the proven-correct form.
// ---------------------------------------------------------------------------
__global__ __launch_bounds__(BLK) void chamfer_main(
    const float* __restrict__ tmpl, const float* __restrict__ src,
    float* __restrict__ partial, float* __restrict__ out)
{
    __shared__ __align__(16) short lds[32 * 512];   // 32 KB: 32 A-tiles
    const int bd  = blockIdx.z;     // 0..7
    const int seg = blockIdx.y;     // 0..MSEG-1
    const int qb  = blockIdx.x;     // 0..15
    const int b = bd >> 1, dir = bd & 1;
    const float* qp = (dir ? src : tmpl) + (size_t)b * NPTS * 3;
    const float* rp = (dir ? tmpl : src) + (size_t)b * NPTS * 3;
    const int tid = threadIdx.x, wid = tid >> 6, lane = tid & 63;

    if ((blockIdx.x | blockIdx.y | blockIdx.z | tid) == 0) out[0] = 0.f;

    // ---- build this segment's A-fragments directly in LDS ----
    const int rbase = seg * 1024;
#pragma unroll
    for (int rr = 0; rr < 4; rr++) {
        const int i = rr * BLK + tid;               // ref idx within segment
        const float* p = rp + (size_t)(rbase + i) * 3;
        const float x = p[0], y = p[1], z = p[2];
        const unsigned short xh = f2bf(x), yh = f2bf(y), zh = f2bf(z);
        const unsigned short xl = f2bf(x - bf2f(xh));
        const unsigned short yl = f2bf(y - bf2f(yh));
        const unsigned short zl = f2bf(z - bf2f(zh));
        const float w = fmaf(x, x, fmaf(y, y, z * z));
        const unsigned short wh = f2bf(w);
        const unsigned short wl = f2bf(w - bf2f(wh));
        const short8v a0 = {(short)xh, (short)yh, (short)zh, (short)xl,
                            (short)yl, (short)zl, (short)xh, (short)yh};
        const short8v a1 = {(short)zh, (short)wh, (short)wl, 0, 0, 0, 0, 0};
        short* ap = lds + (i >> 5) * 512;
        *(short8v*)(ap + (i & 31) * 8)        = a0;   // lane-contiguous 16B
        *(short8v*)(ap + ((i & 31) + 32) * 8) = a1;   // -> conflict-free
    }

    // ---- build 4 B-fragments in registers (identical split math) ----
    const int qt0 = qb * 16 + wid * QPW;            // first of 4 query tiles
    short8v bf[QPW];
#pragma unroll
    for (int p = 0; p < QPW; p++) {
        const int qid = (qt0 + p) * 32 + (lane & 31);
        const float x = qp[3 * qid], y = qp[3 * qid + 1], z = qp[3 * qid + 2];
        const float mx = -2.f * x, my = -2.f * y, mz = -2.f * z;
        const unsigned short mxh = f2bf(mx), myh = f2bf(my), mzh = f2bf(mz);
        const unsigned short mxl = f2bf(mx - bf2f(mxh));
        const unsigned short myl = f2bf(my - bf2f(myh));
        const unsigned short mzl = f2bf(mz - bf2f(mzh));
        const unsigned short ONE = 0x3F80;  // bf16 1.0
        const short8v b0 = {(short)mxh, (short)myh, (short)mzh, (short)mxh,
                            (short)myh, (short)mzh, (short)mxl, (short)myl};
        const short8v b1 = {(short)mzl, (short)ONE, (short)ONE, 0, 0, 0, 0, 0};
        bf[p] = (lane < 32) ? b0 : b1;
    }

    float mn[QPW];
#pragma unroll
    for (int p = 0; p < QPW; p++) mn[p] = 3.4e38f;

    __syncthreads();   // the kernel's only barrier

    const short* lbase = lds + lane * 8;
#pragma unroll 4
    for (int t = 0; t < 32; t++) {
        const short8v a = *(const short8v*)(lbase + t * 512);
#pragma unroll
        for (int p = 0; p < QPW; p++) {
            f32x16 d = __builtin_amdgcn_mfma_f32_32x32x16_bf16(
                a, bf[p], (f32x16)(0.f), 0, 0, 0);
            const float g0 = min3f(d[0],  d[1],  d[2]);
            const float g1 = min3f(d[3],  d[4],  d[5]);
            const float g2 = min3f(d[6],  d[7],  d[8]);
            const float g3 = min3f(d[9],  d[10], d[11]);
            const float g4 = min3f(d[12], d[13], d[14]);
            mn[p] = min3f(mn[p], g0, g1);
            mn[p] = min3f(mn[p], g2, g3);
            mn[p] = min3f(mn[p], g4, d[15]);
        }
    }

    const size_t sb = ((size_t)bd * MSEG + seg) * NPTS;
#pragma unroll
    for (int p = 0; p < QPW; p++) {
        mn[p] = fminf(mn[p], __shfl_xor(mn[p], 32, 64));
        if (lane < 32)
            partial[sb + (size_t)(qt0 + p) * 32 + lane] = mn[p];
    }
}

// ---------------------------------------------------------------------------
// P2: combine MSEG segment mins, add |q|^2 (exact fp32), clamp, sqrt, mean.
// ---------------------------------------------------------------------------
__global__ __launch_bounds__(BLK) void chamfer_reduce(
    const float* __restrict__ tmpl, const float* __restrict__ src,
    const float* __restrict__ partial, float* __restrict__ out)
{
    const int t  = blockIdx.x * BLK + threadIdx.x;  // 0 .. 8*NPTS-1
    const int bd = t >> 13;
    const int qi = t & (NPTS - 1);
    const int b  = bd >> 1;
    const int dir = bd & 1;
    const float* qp = (dir ? src : tmpl) + (size_t)b * NPTS * 3;
    const float qx = qp[3 * qi + 0];
    const float qy = qp[3 * qi + 1];
    const float qz = qp[3 * qi + 2];
    const float sq = qx * qx + qy * qy + qz * qz;

    float m = 3.4e38f;
#pragma unroll
    for (int s = 0; s < MSEG; s++)
        m = fminf(m, partial[((size_t)bd * MSEG + s) * NPTS + qi]);
    float v = sqrtf(fmaxf(sq + m, 0.f));

#pragma unroll
    for (int off = 32; off > 0; off >>= 1)
        v += __shfl_down(v, off, 64);

    __shared__ float wsum[BLK / 64];
    const int lane = threadIdx.x & 63;
    const int wid  = threadIdx.x >> 6;
    if (lane == 0) wsum[wid] = v;
    __syncthreads();
    if (threadIdx.x == 0) {
        float s = 0.f;
#pragma unroll
        for (int w = 0; w < BLK / 64; w++) s += wsum[w];
        atomicAdd(out, s * (1.0f / 65536.0f));
    }
}

extern "C" void kernel_launch(void* const* d_in, const int* in_sizes, int n_in,
                              void* d_out, int out_size, void* d_ws, size_t ws_size,
                              hipStream_t stream) {
    const float* tmpl = (const float*)d_in[0];
    const float* src  = (const float*)d_in[1];
    float* out = (float*)d_out;

    float* partial = (float*)d_ws;   // 2 MB: 8 bd x MSEG x NPTS floats

    dim3 g1(16, MSEG, 2 * NB);   // 16 x 8 x 8 = 1024 blocks (4/CU)
    chamfer_main<<<g1, BLK, 0, stream>>>(tmpl, src, partial, out);

    chamfer_reduce<<<(2 * NB * NPTS) / BLK, BLK, 0, stream>>>(tmpl, src, partial, out);
}